// Round 3
// baseline (69.266 us; speedup 1.0000x reference)
//
#include <hip/hip_runtime.h>
#include <hip/hip_bf16.h>

// Problem dims (fixed by the reference): B=64, T=2048, D=256
#define BB  64
#define TT  2048
#define DD  256
#define EPSV 1e-7f
#define TILE_R 32   // rows per tile
#define NTILE  8    // tiles per block
#define NBLK   512  // blocks: NBLK*NTILE*TILE_R == BB*TT

typedef __attribute__((ext_vector_type(8))) short bf16x8;   // MFMA A/B fragment (4 VGPR)
typedef __attribute__((ext_vector_type(4))) float f32x4;    // MFMA C/D fragment

__device__ __forceinline__ ushort f2bf(float f) {           // RNE (used in prep only)
    union { float f; unsigned u; } v; v.f = f;
    unsigned u = v.u;
    unsigned r = (u + 0x7FFFu + ((u >> 16) & 1u)) >> 16;
    return (ushort)r;
}

__device__ __forceinline__ float bf2f(ushort h) {
    union { unsigned u; float f; } v; v.u = ((unsigned)h) << 16;
    return v.f;
}

// pack two f32 -> two bf16 (round-half-up) in ONE v_perm + 2 adds
__device__ __forceinline__ unsigned pkbf(float lo, float hi) {
    union { float f; unsigned u; } a, b;
    a.f = lo; b.f = hi;
    return __builtin_amdgcn_perm(b.u + 0x8000u, a.u + 0x8000u, 0x07060302u);
}

__device__ __forceinline__ float tanh_fast(float x) {
    float e = __expf(2.0f * x);
    return 1.0f - 2.0f * __builtin_amdgcn_rcpf(e + 1.0f);
}

// ---------------------------------------------------------------------------
// prep: blocks 0..255   -> bias partials (block b*4+q covers d in [q*64, q*64+64))
//       blocks 256..287 -> W_frag: context_w (f32 [256][256]) -> bf16 MFMA B-frag order
// ---------------------------------------------------------------------------
__global__ __launch_bounds__(256) void prep_kernel(
    const float* __restrict__ aspect, const float* __restrict__ sentence,
    const float* __restrict__ context_w, const float* __restrict__ aspect_w,
    const float* __restrict__ sent_w,
    float* __restrict__ bias_part, ushort* __restrict__ wfrag_ws)
{
    const int blk = blockIdx.x, tid = threadIdx.x;
    if (blk < 256) {
        const int b = blk >> 2, q = blk & 3, e = tid;
        float s = 0.f;
        #pragma unroll 4
        for (int dd = 0; dd < 64; ++dd) {
            const int d = q * 64 + dd;
            s = fmaf(aspect[b * DD + d],   aspect_w[d * DD + e], s);
            s = fmaf(sentence[b * DD + d], sent_w[d * DD + e],   s);
        }
        bias_part[blk * DD + e] = s;
    } else {
        const int flat = (blk - 256) * 256 + tid;    // 0..8191
        const int lane = flat & 63;
        const int kn   = flat >> 6;
        const int kk   = kn >> 4;
        const int n    = kn & 15;
        const int krow = kk * 32 + ((lane >> 4) << 3);
        const int col  = n * 16 + (lane & 15);
        bf16x8 v;
        #pragma unroll
        for (int j = 0; j < 8; ++j)
            v[j] = (short)f2bf(context_w[(size_t)(krow + j) * DD + col]);
        *reinterpret_cast<bf16x8*>(wfrag_ws + (size_t)flat * 8) = v;
    }
}

// ---------------------------------------------------------------------------
// attn_main: 512 blocks x 512 thr (8 waves), 8 tiles of 32 rows each.
// 2 blocks/CU (LDS 44KB, VGPR<=128) -> cross-block phase overlap.
// Per tile: [issue loads t+1][GEMM][gpart wr][barrier][evals+wsum][stage t+1][barrier]
// ---------------------------------------------------------------------------
__global__ __launch_bounds__(512, 4) void attn_main(
    const float* __restrict__ ctx, const int* __restrict__ mask,
    const float* __restrict__ attend_w,
    const float* __restrict__ bias_part, const ushort* __restrict__ wfrag_ws,
    float* __restrict__ partial_ws, float* __restrict__ esum_ws)
{
    __shared__ ushort ctx_lds[2][TILE_R * 256];  // 2 x 16KB, 512B row pitch, XOR swizzle
    __shared__ float  bias_lds[256];
    __shared__ float  aw_lds[256];
    __shared__ float  mask_lds[256];
    __shared__ float  gpart[TILE_R][8];
    __shared__ float  esw[8];
    __shared__ float  part_d[8][256];

    const int tid  = threadIdx.x;
    const int wave = tid >> 6;
    const int lane = tid & 63;
    const int blk  = blockIdx.x;
    const int b    = blk >> 3;               // 8 blocks per batch element

    if (tid < 256) {
        bias_lds[tid] = bias_part[(b * 4 + 0) * DD + tid] + bias_part[(b * 4 + 1) * DD + tid]
                      + bias_part[(b * 4 + 2) * DD + tid] + bias_part[(b * 4 + 3) * DD + tid];
        aw_lds[tid]   = attend_w[tid];
        mask_lds[tid] = (float)mask[blk * 256 + tid];
    }

    // ---- preload this wave's 16 B-fragments (cols wave*32 .. +32): 64 VGPR ----
    bf16x8 Bf[8][2];
    {
        const bf16x8* wf = reinterpret_cast<const bf16x8*>(wfrag_ws);
        #pragma unroll
        for (int kk = 0; kk < 8; ++kk) {
            Bf[kk][0] = wf[(kk * 16 + wave * 2 + 0) * 64 + lane];
            Bf[kk][1] = wf[(kk * 16 + wave * 2 + 1) * 64 + lane];
        }
    }

    const float4* src = reinterpret_cast<const float4*>(ctx);

    // ---- prologue: stage tile 0 ----
    {
        const size_t base4 = (size_t)(blk * NTILE) * 2048;   // float4 per tile = 2048
        char* dst = reinterpret_cast<char*>(ctx_lds[0]);
        #pragma unroll
        for (int i = 0; i < 2; ++i) {
            const int c = i * 512 + tid;                     // 8-float chunk index
            const float4 v0 = src[base4 + c * 2 + 0];
            const float4 v1 = src[base4 + c * 2 + 1];
            const int row = c >> 5, c8 = c & 31;
            uint4 u;
            u.x = pkbf(v0.x, v0.y); u.y = pkbf(v0.z, v0.w);
            u.z = pkbf(v1.x, v1.y); u.w = pkbf(v1.z, v1.w);
            *reinterpret_cast<uint4*>(dst + row * 512 + ((c8 * 16) ^ ((row & 7) << 4))) = u;
        }
    }
    __syncthreads();

    float accd[4] = {0.f, 0.f, 0.f, 0.f};
    float es_tot = 0.f;

    for (int it = 0; it < NTILE; ++it) {
        const int cur = it & 1;

        // ---- issue next tile's global loads (consumed after barrier A) ----
        float4 sreg[4];
        if (it + 1 < NTILE) {
            const size_t base4 = (size_t)(blk * NTILE + it + 1) * 2048;
            #pragma unroll
            for (int i = 0; i < 2; ++i) {
                const int c = i * 512 + tid;
                sreg[2 * i + 0] = src[base4 + c * 2 + 0];
                sreg[2 * i + 1] = src[base4 + c * 2 + 1];
            }
        }

        // ---- GEMM: wave covers 32 rows x its 32 cols ----
        const char* lb = reinterpret_cast<const char*>(ctx_lds[cur]);
        f32x4 acc[2][2];
        #pragma unroll
        for (int rt = 0; rt < 2; ++rt) {
            acc[rt][0] = (f32x4){0.f, 0.f, 0.f, 0.f};
            acc[rt][1] = (f32x4){0.f, 0.f, 0.f, 0.f};
        }
        #pragma unroll
        for (int rt = 0; rt < 2; ++rt) {
            const int row = rt * 16 + (lane & 15);
            const char* ab = lb + row * 512;
            const int asw = (row & 7) << 4;
            #pragma unroll
            for (int kk = 0; kk < 8; ++kk) {
                const bf16x8 a = *reinterpret_cast<const bf16x8*>(
                    ab + ((kk * 64 + ((lane >> 4) << 4)) ^ asw));
                acc[rt][0] = __builtin_amdgcn_mfma_f32_16x16x32_bf16(a, Bf[kk][0], acc[rt][0], 0, 0, 0);
                acc[rt][1] = __builtin_amdgcn_mfma_f32_16x16x32_bf16(a, Bf[kk][1], acc[rt][1], 0, 0, 0);
            }
        }

        // ---- epilogue: partial g over this wave's 32 cols -> gpart ----
        {
            const int c0 = wave * 32 + (lane & 15), c1 = c0 + 16;
            const float bs0 = bias_lds[c0], aw0 = aw_lds[c0];
            const float bs1 = bias_lds[c1], aw1 = aw_lds[c1];
            #pragma unroll
            for (int rt = 0; rt < 2; ++rt) {
                float gp[4];
                #pragma unroll
                for (int j = 0; j < 4; ++j)
                    gp[j] = tanh_fast(acc[rt][0][j] + bs0) * aw0
                          + tanh_fast(acc[rt][1][j] + bs1) * aw1;
                #pragma unroll
                for (int off = 1; off < 16; off <<= 1) {
                    #pragma unroll
                    for (int j = 0; j < 4; ++j) gp[j] += __shfl_xor(gp[j], off);
                }
                if ((lane & 15) == 0) {
                    const int r = rt * 16 + ((lane >> 4) << 2);
                    gpart[r + 0][wave] = gp[0]; gpart[r + 1][wave] = gp[1];
                    gpart[r + 2][wave] = gp[2]; gpart[r + 3][wave] = gp[3];
                }
            }
        }
        __syncthreads();   // barrier A: gpart complete; buf[cur^1] free

        // ---- evals (per-wave, redundant across lanes) + fused weighted sum ----
        {
            float ev[4];
            #pragma unroll
            for (int rr = 0; rr < 4; ++rr) {
                const int r = wave * 4 + rr;
                const float4 g0 = *reinterpret_cast<const float4*>(&gpart[r][0]);
                const float4 g1 = *reinterpret_cast<const float4*>(&gpart[r][4]);
                const float g = ((g0.x + g0.y) + (g0.z + g0.w))
                              + ((g1.x + g1.y) + (g1.z + g1.w));
                ev[rr] = __expf(g) * mask_lds[it * TILE_R + r];
                es_tot += ev[rr];
            }
            #pragma unroll
            for (int rr = 0; rr < 4; ++rr) {
                const int r = wave * 4 + rr;
                const ushort4 hv = *reinterpret_cast<const ushort4*>(
                    lb + r * 512 + ((lane * 8) ^ ((r & 7) << 4)));
                accd[0] = fmaf(bf2f(hv.x), ev[rr], accd[0]);
                accd[1] = fmaf(bf2f(hv.y), ev[rr], accd[1]);
                accd[2] = fmaf(bf2f(hv.z), ev[rr], accd[2]);
                accd[3] = fmaf(bf2f(hv.w), ev[rr], accd[3]);
            }
        }

        // ---- convert + write next tile into the other buffer ----
        if (it + 1 < NTILE) {
            char* dst = reinterpret_cast<char*>(ctx_lds[cur ^ 1]);
            #pragma unroll
            for (int i = 0; i < 2; ++i) {
                const int c = i * 512 + tid;
                const int row = c >> 5, c8 = c & 31;
                uint4 u;
                u.x = pkbf(sreg[2 * i].x,     sreg[2 * i].y);
                u.y = pkbf(sreg[2 * i].z,     sreg[2 * i].w);
                u.z = pkbf(sreg[2 * i + 1].x, sreg[2 * i + 1].y);
                u.w = pkbf(sreg[2 * i + 1].z, sreg[2 * i + 1].w);
                *reinterpret_cast<uint4*>(dst + row * 512 + ((c8 * 16) ^ ((row & 7) << 4))) = u;
            }
        }
        __syncthreads();   // barrier B: buf[cur^1] staged
    }

    // ---- block epilogue ----
    *reinterpret_cast<float4*>(&part_d[wave][lane * 4]) = (float4){accd[0], accd[1], accd[2], accd[3]};
    if (lane == 0) esw[wave] = es_tot;
    __syncthreads();
    if (tid < 256) {
        float s = 0.f;
        #pragma unroll
        for (int w = 0; w < 8; ++w) s += part_d[w][tid];
        partial_ws[blk * DD + tid] = s;
    }
    if (tid == 0) {
        float e = 0.f;
        #pragma unroll
        for (int w = 0; w < 8; ++w) e += esw[w];
        esum_ws[blk] = e;
    }
}

// ---------------------------------------------------------------------------
// finalize: out[b,d] = (sum_i partial) / (sum_i esum + EPS) + sentence[b,d]
// ---------------------------------------------------------------------------
__global__ __launch_bounds__(256) void finalize_kernel(
    const float* __restrict__ sentence, const float* __restrict__ partial_ws,
    const float* __restrict__ esum_ws, float* __restrict__ out)
{
    const int b = blockIdx.x, d = threadIdx.x;
    float es = 0.f, s = 0.f;
    #pragma unroll
    for (int i = 0; i < 8; ++i) {
        es += esum_ws[b * 8 + i];
        s  += partial_ws[(size_t)(b * 8 + i) * DD + d];
    }
    out[b * DD + d] = s / (es + EPSV) + sentence[b * DD + d];
}

extern "C" void kernel_launch(void* const* d_in, const int* in_sizes, int n_in,
                              void* d_out, int out_size, void* d_ws, size_t ws_size,
                              hipStream_t stream)
{
    const float* ctx       = (const float*)d_in[0];
    const float* aspect    = (const float*)d_in[1];
    const float* sentence  = (const float*)d_in[2];
    const int*   mask      = (const int*)  d_in[3];
    const float* context_w = (const float*)d_in[4];
    const float* aspect_w  = (const float*)d_in[5];
    const float* sent_w    = (const float*)d_in[6];
    const float* attend_w  = (const float*)d_in[7];
    float* out = (float*)d_out;

    char* ws = (char*)d_ws;
    ushort* wfrag_ws   = (ushort*)(ws);                          // 131072 B
    float*  bias_part  = (float*) (ws + 131072);                 // 262144 B
    float*  esum_ws    = (float*) (ws + 131072 + 262144);        //   2048 B
    float*  partial_ws = (float*) (ws + 131072 + 262144 + 2048); // 524288 B

    prep_kernel<<<288, 256, 0, stream>>>(aspect, sentence, context_w, aspect_w, sent_w,
                                         bias_part, wfrag_ws);
    attn_main<<<NBLK, 512, 0, stream>>>(ctx, mask, attend_w, bias_part, wfrag_ws,
                                        partial_ws, esum_ws);
    finalize_kernel<<<BB, 256, 0, stream>>>(sentence, partial_ws, esum_ws, out);
}

// Round 4
// 63.733 us; speedup vs baseline: 1.0868x; 1.0868x over previous
//
#include <hip/hip_runtime.h>
#include <hip/hip_bf16.h>

// Problem dims (fixed by the reference): B=64, T=2048, D=256
#define BB  64
#define TT  2048
#define DD  256
#define EPSV 1e-7f
#define TILE_R 64   // rows per tile
#define NTILE  8    // tiles per block
#define NBLK   256  // blocks: NBLK*NTILE*TILE_R == BB*TT ; exactly 1 block/CU

typedef __attribute__((ext_vector_type(8))) short bf16x8;   // MFMA A/B fragment (4 VGPR)
typedef __attribute__((ext_vector_type(4))) float f32x4;    // MFMA C/D fragment

#define GLOAD16(g, l) __builtin_amdgcn_global_load_lds( \
    (const __attribute__((address_space(1))) unsigned int*)(g), \
    (__attribute__((address_space(3))) unsigned int*)(l), 16, 0, 0)

__device__ __forceinline__ ushort f2bf(float f) {           // RNE (prep only)
    union { float f; unsigned u; } v; v.f = f;
    unsigned u = v.u;
    unsigned r = (u + 0x7FFFu + ((u >> 16) & 1u)) >> 16;
    return (ushort)r;
}

__device__ __forceinline__ float bf2f(unsigned h16) {       // low 16 bits = bf16
    union { unsigned u; float f; } v; v.u = h16 << 16;
    return v.f;
}

// pack two f32 -> two bf16 (round-half-up): [bf(lo), bf(hi)]
__device__ __forceinline__ unsigned pkbf(float lo, float hi) {
    union { float f; unsigned u; } a, b;
    a.f = lo; b.f = hi;
    return __builtin_amdgcn_perm(b.u + 0x8000u, a.u + 0x8000u, 0x07060302u);
}

__device__ __forceinline__ float tanh_fast(float x) {
    float e = __expf(2.0f * x);
    return 1.0f - 2.0f * __builtin_amdgcn_rcpf(e + 1.0f);
}

// ---------------------------------------------------------------------------
// prep: blocks 0..255   -> bias partials (block b*4+q covers d in [q*64, q*64+64))
//       blocks 256..287 -> W_frag: context_w (f32 [256][256]) -> bf16 MFMA B-frag order
// ---------------------------------------------------------------------------
__global__ __launch_bounds__(256) void prep_kernel(
    const float* __restrict__ aspect, const float* __restrict__ sentence,
    const float* __restrict__ context_w, const float* __restrict__ aspect_w,
    const float* __restrict__ sent_w,
    float* __restrict__ bias_part, ushort* __restrict__ wfrag_ws)
{
    const int blk = blockIdx.x, tid = threadIdx.x;
    if (blk < 256) {
        const int b = blk >> 2, q = blk & 3, e = tid;
        float s = 0.f;
        #pragma unroll 4
        for (int dd = 0; dd < 64; ++dd) {
            const int d = q * 64 + dd;
            s = fmaf(aspect[b * DD + d],   aspect_w[d * DD + e], s);
            s = fmaf(sentence[b * DD + d], sent_w[d * DD + e],   s);
        }
        bias_part[blk * DD + e] = s;
    } else {
        const int flat = (blk - 256) * 256 + tid;    // 0..8191
        const int lane = flat & 63;
        const int kn   = flat >> 6;
        const int kk   = kn >> 4;
        const int n    = kn & 15;
        const int krow = kk * 32 + ((lane >> 4) << 3);
        const int col  = n * 16 + (lane & 15);
        bf16x8 v;
        #pragma unroll
        for (int j = 0; j < 8; ++j)
            v[j] = (short)f2bf(context_w[(size_t)(krow + j) * DD + col]);
        *reinterpret_cast<bf16x8*>(wfrag_ws + (size_t)flat * 8) = v;
    }
}

// ---------------------------------------------------------------------------
// attn_main: 256 blocks x 1024 thr (16 waves), 8 tiles of 64 rows.
// fp32 tile streams in via global_load_lds (issue at iter i, consumed at i+1's
// wave-local convert -> loads in flight continuously). bf16 dbuf for MFMA A +
// weighted sum. Wave (cg=wave&7, rh=wave>>3) computes rows rh*32..+31 x cols cg*32..+31.
// 2 barriers per tile.
// ---------------------------------------------------------------------------
__global__ __launch_bounds__(1024, 4) void attn_main(
    const float* __restrict__ ctx, const int* __restrict__ mask,
    const float* __restrict__ attend_w,
    const float* __restrict__ bias_part, const ushort* __restrict__ wfrag_ws,
    float* __restrict__ partial_ws, float* __restrict__ esum_ws)
{
    __shared__ __align__(16) char stage[65536];          // fp32 tile, row-linear (1KB/row)
    __shared__ __align__(16) char bfb[2][32768];         // bf16 tiles, 512B pitch, XOR swizzle
    __shared__ float bias_lds[256];
    __shared__ float aw_lds[256];
    __shared__ float mask_lds[512];
    __shared__ float gpart[TILE_R][8];
    __shared__ float esw[16];

    const int tid  = threadIdx.x;
    const int wave = tid >> 6;
    const int lane = tid & 63;
    const int blk  = blockIdx.x;
    const int b    = blk >> 2;                 // 4 blocks per batch element
    const int cg   = wave & 7;                 // col group (32 cols)
    const int rh   = wave >> 3;                // row half (32 rows)

    if (tid < 256) {
        bias_lds[tid] = bias_part[(b * 4 + 0) * DD + tid] + bias_part[(b * 4 + 1) * DD + tid]
                      + bias_part[(b * 4 + 2) * DD + tid] + bias_part[(b * 4 + 3) * DD + tid];
        aw_lds[tid]   = attend_w[tid];
    }
    if (tid >= 512 && tid < 1024) {            // different waves than above
        const int m = tid - 512;
        mask_lds[m] = (float)mask[blk * 512 + m];
    }

    // ---- preload this wave's 16 B-fragments (cols cg*32 .. +31): 64 VGPR ----
    bf16x8 Bf[8][2];
    {
        const bf16x8* wf = reinterpret_cast<const bf16x8*>(wfrag_ws);
        #pragma unroll
        for (int kk = 0; kk < 8; ++kk) {
            Bf[kk][0] = wf[(kk * 16 + cg * 2 + 0) * 64 + lane];
            Bf[kk][1] = wf[(kk * 16 + cg * 2 + 1) * 64 + lane];
        }
    }

    const char* gctx = reinterpret_cast<const char*>(ctx);
    // wave w owns stage rows 4w..4w+3 (4KB) for both gload and convert

    // ---- prologue: load tile 0, convert, issue tile 1 ----
    {
        const char* g0 = gctx + (size_t)(blk * NTILE + 0) * 65536 + wave * 4096 + lane * 16;
        char* ld = stage + wave * 4096;
        #pragma unroll
        for (int j = 0; j < 4; ++j) GLOAD16(g0 + j * 1024, ld + j * 1024);
        asm volatile("s_waitcnt vmcnt(0)" ::: "memory");
        __builtin_amdgcn_sched_barrier(0);
        #pragma unroll
        for (int p = 0; p < 2; ++p) {
            const char* sb = stage + wave * 4096 + p * 2048;
            const float4 f0 = *reinterpret_cast<const float4*>(sb + lane * 16);
            const float4 f1 = *reinterpret_cast<const float4*>(sb + 1024 + lane * 16);
            const int r0 = wave * 4 + p * 2, r1 = r0 + 1;
            uint2 u0, u1;
            u0.x = pkbf(f0.x, f0.y); u0.y = pkbf(f0.z, f0.w);
            u1.x = pkbf(f1.x, f1.y); u1.y = pkbf(f1.z, f1.w);
            *reinterpret_cast<uint2*>(bfb[0] + r0 * 512 + ((lane * 8) ^ ((r0 & 7) << 4))) = u0;
            *reinterpret_cast<uint2*>(bfb[0] + r1 * 512 + ((lane * 8) ^ ((r1 & 7) << 4))) = u1;
        }
        asm volatile("s_waitcnt lgkmcnt(0)" ::: "memory");
        __builtin_amdgcn_sched_barrier(0);
        const char* g1 = gctx + (size_t)(blk * NTILE + 1) * 65536 + wave * 4096 + lane * 16;
        #pragma unroll
        for (int j = 0; j < 4; ++j) GLOAD16(g1 + j * 1024, ld + j * 1024);
    }
    __syncthreads();

    float accd[4] = {0.f, 0.f, 0.f, 0.f};
    float es_tot = 0.f;

    for (int it = 0; it < NTILE; ++it) {
        const int cur = it & 1;
        const char* lb = bfb[cur];

        // ---- GEMM: 32 rows (rh) x 32 cols (cg), K=256 ----
        f32x4 acc[2][2];
        #pragma unroll
        for (int rt = 0; rt < 2; ++rt) {
            acc[rt][0] = (f32x4){0.f, 0.f, 0.f, 0.f};
            acc[rt][1] = (f32x4){0.f, 0.f, 0.f, 0.f};
        }
        #pragma unroll
        for (int rt = 0; rt < 2; ++rt) {
            const int row = rh * 32 + rt * 16 + (lane & 15);
            const char* ab = lb + row * 512;
            const int asw = (row & 7) << 4;
            #pragma unroll
            for (int kk = 0; kk < 8; ++kk) {
                const bf16x8 a = *reinterpret_cast<const bf16x8*>(
                    ab + ((kk * 64 + ((lane >> 4) << 4)) ^ asw));
                acc[rt][0] = __builtin_amdgcn_mfma_f32_16x16x32_bf16(a, Bf[kk][0], acc[rt][0], 0, 0, 0);
                acc[rt][1] = __builtin_amdgcn_mfma_f32_16x16x32_bf16(a, Bf[kk][1], acc[rt][1], 0, 0, 0);
            }
        }

        // ---- epilogue: partial g over this wave's 32 cols -> gpart ----
        {
            const int c0 = cg * 32 + (lane & 15), c1 = c0 + 16;
            const float bs0 = bias_lds[c0], aw0 = aw_lds[c0];
            const float bs1 = bias_lds[c1], aw1 = aw_lds[c1];
            #pragma unroll
            for (int rt = 0; rt < 2; ++rt) {
                float gp[4];
                #pragma unroll
                for (int j = 0; j < 4; ++j)
                    gp[j] = tanh_fast(acc[rt][0][j] + bs0) * aw0
                          + tanh_fast(acc[rt][1][j] + bs1) * aw1;
                #pragma unroll
                for (int off = 1; off < 16; off <<= 1) {
                    #pragma unroll
                    for (int j = 0; j < 4; ++j) gp[j] += __shfl_xor(gp[j], off);
                }
                if ((lane & 15) == 0) {
                    const int r = rh * 32 + rt * 16 + ((lane >> 4) << 2);
                    gpart[r + 0][cg] = gp[0]; gpart[r + 1][cg] = gp[1];
                    gpart[r + 2][cg] = gp[2]; gpart[r + 3][cg] = gp[3];
                }
            }
        }
        __syncthreads();   // gpart complete

        // ---- evals + fused weighted sum: wave handles tile rows wave*4..+3 ----
        #pragma unroll
        for (int rr = 0; rr < 4; ++rr) {
            const int r = wave * 4 + rr;
            const float4 g0 = *reinterpret_cast<const float4*>(&gpart[r][0]);
            const float4 g1 = *reinterpret_cast<const float4*>(&gpart[r][4]);
            const float g = ((g0.x + g0.y) + (g0.z + g0.w))
                          + ((g1.x + g1.y) + (g1.z + g1.w));
            const float ev = __expf(g) * mask_lds[it * TILE_R + r];
            es_tot += ev;
            const uint2 hv = *reinterpret_cast<const uint2*>(
                lb + r * 512 + ((lane * 8) ^ ((r & 7) << 4)));
            accd[0] = fmaf(bf2f(hv.x & 0xffffu), ev, accd[0]);
            accd[1] = fmaf(bf2f(hv.x >> 16),     ev, accd[1]);
            accd[2] = fmaf(bf2f(hv.y & 0xffffu), ev, accd[2]);
            accd[3] = fmaf(bf2f(hv.y >> 16),     ev, accd[3]);
        }

        // ---- wave-local: convert staged tile (it+1) and re-issue gload (it+2) ----
        if (it + 1 < NTILE) {
            asm volatile("s_waitcnt vmcnt(0)" ::: "memory");
            __builtin_amdgcn_sched_barrier(0);
            char* dst = bfb[cur ^ 1];
            #pragma unroll
            for (int p = 0; p < 2; ++p) {
                const char* sb = stage + wave * 4096 + p * 2048;
                const float4 f0 = *reinterpret_cast<const float4*>(sb + lane * 16);
                const float4 f1 = *reinterpret_cast<const float4*>(sb + 1024 + lane * 16);
                const int r0 = wave * 4 + p * 2, r1 = r0 + 1;
                uint2 u0, u1;
                u0.x = pkbf(f0.x, f0.y); u0.y = pkbf(f0.z, f0.w);
                u1.x = pkbf(f1.x, f1.y); u1.y = pkbf(f1.z, f1.w);
                *reinterpret_cast<uint2*>(dst + r0 * 512 + ((lane * 8) ^ ((r0 & 7) << 4))) = u0;
                *reinterpret_cast<uint2*>(dst + r1 * 512 + ((lane * 8) ^ ((r1 & 7) << 4))) = u1;
            }
            if (it + 2 < NTILE) {
                asm volatile("s_waitcnt lgkmcnt(0)" ::: "memory");
                __builtin_amdgcn_sched_barrier(0);
                const char* gn = gctx + (size_t)(blk * NTILE + it + 2) * 65536
                               + wave * 4096 + lane * 16;
                char* ld = stage + wave * 4096;
                #pragma unroll
                for (int j = 0; j < 4; ++j) GLOAD16(gn + j * 1024, ld + j * 1024);
            }
        }
        __syncthreads();   // bf16[cur^1] staged; bf16[cur] free next iter
    }

    // ---- block epilogue: overlay partials on stage (dead), combine ----
    {
        float* part = reinterpret_cast<float*>(stage);
        *reinterpret_cast<float4*>(part + wave * 256 + lane * 4) =
            (float4){accd[0], accd[1], accd[2], accd[3]};
        if (lane == 0) esw[wave] = es_tot;
    }
    __syncthreads();
    if (tid < 256) {
        const float* part = reinterpret_cast<const float*>(stage);
        float s = 0.f;
        #pragma unroll
        for (int w = 0; w < 16; ++w) s += part[w * 256 + tid];
        partial_ws[blk * DD + tid] = s;
    }
    if (tid == 0) {
        float e = 0.f;
        #pragma unroll
        for (int w = 0; w < 16; ++w) e += esw[w];
        esum_ws[blk] = e;
    }
}

// ---------------------------------------------------------------------------
// finalize: out[b,d] = (sum_i partial) / (sum_i esum + EPS) + sentence[b,d]
// ---------------------------------------------------------------------------
__global__ __launch_bounds__(256) void finalize_kernel(
    const float* __restrict__ sentence, const float* __restrict__ partial_ws,
    const float* __restrict__ esum_ws, float* __restrict__ out)
{
    const int b = blockIdx.x, d = threadIdx.x;
    float es = 0.f, s = 0.f;
    #pragma unroll
    for (int i = 0; i < 4; ++i) {
        es += esum_ws[b * 4 + i];
        s  += partial_ws[(size_t)(b * 4 + i) * DD + d];
    }
    out[b * DD + d] = s / (es + EPSV) + sentence[b * DD + d];
}

extern "C" void kernel_launch(void* const* d_in, const int* in_sizes, int n_in,
                              void* d_out, int out_size, void* d_ws, size_t ws_size,
                              hipStream_t stream)
{
    const float* ctx       = (const float*)d_in[0];
    const float* aspect    = (const float*)d_in[1];
    const float* sentence  = (const float*)d_in[2];
    const int*   mask      = (const int*)  d_in[3];
    const float* context_w = (const float*)d_in[4];
    const float* aspect_w  = (const float*)d_in[5];
    const float* sent_w    = (const float*)d_in[6];
    const float* attend_w  = (const float*)d_in[7];
    float* out = (float*)d_out;

    char* ws = (char*)d_ws;
    ushort* wfrag_ws   = (ushort*)(ws);                          // 131072 B
    float*  bias_part  = (float*) (ws + 131072);                 // 262144 B
    float*  esum_ws    = (float*) (ws + 131072 + 262144);        //   1024 B
    float*  partial_ws = (float*) (ws + 131072 + 262144 + 1024); // 262144 B

    prep_kernel<<<288, 256, 0, stream>>>(aspect, sentence, context_w, aspect_w, sent_w,
                                         bias_part, wfrag_ws);
    attn_main<<<NBLK, 1024, 0, stream>>>(ctx, mask, attend_w, bias_part, wfrag_ws,
                                         partial_ws, esum_ws);
    finalize_kernel<<<BB, 256, 0, stream>>>(sentence, partial_ws, esum_ws, out);
}

// Round 5
// 50.836 us; speedup vs baseline: 1.3625x; 1.2537x over previous
//
#include <hip/hip_runtime.h>
#include <hip/hip_bf16.h>

// Problem dims (fixed by the reference): B=64, T=2048, D=256
#define BB  64
#define TT  2048
#define DD  256
#define EPSV 1e-7f
#define TILE_R 32   // rows per tile
#define NTILE  8    // tiles per block
#define NBLK   512  // blocks: NBLK*NTILE*TILE_R == BB*TT

typedef __attribute__((ext_vector_type(8))) short bf16x8;   // MFMA A/B fragment (4 VGPR)
typedef __attribute__((ext_vector_type(4))) float f32x4;    // MFMA C/D fragment

__device__ __forceinline__ ushort f2bf(float f) {           // RNE (prep only)
    union { float f; unsigned u; } v; v.f = f;
    unsigned u = v.u;
    unsigned r = (u + 0x7FFFu + ((u >> 16) & 1u)) >> 16;
    return (ushort)r;
}

__device__ __forceinline__ float bf2f(unsigned h16) {       // low 16 bits = bf16
    union { unsigned u; float f; } v; v.u = h16 << 16;
    return v.f;
}

// pack two f32 -> two bf16 (round-half-up): [bf(lo), bf(hi)]
__device__ __forceinline__ unsigned pkbf(float lo, float hi) {
    union { float f; unsigned u; } a, b;
    a.f = lo; b.f = hi;
    return __builtin_amdgcn_perm(b.u + 0x8000u, a.u + 0x8000u, 0x07060302u);
}

__device__ __forceinline__ float tanh_fast(float x) {
    float e = __expf(2.0f * x);
    return 1.0f - 2.0f * __builtin_amdgcn_rcpf(e + 1.0f);
}

// sum over the 16-lane DPP row via rotations (pure VALU, no LDS traffic)
template<int CTRL>
__device__ __forceinline__ float dpp_rot_add(float x) {
    union { float f; int i; } a; a.f = x;
    int r = __builtin_amdgcn_update_dpp(0, a.i, CTRL, 0xF, 0xF, true);
    union { int i; float f; } b; b.i = r;
    return x + b.f;
}
__device__ __forceinline__ float row16_sum(float x) {
    x = dpp_rot_add<0x121>(x);   // row_ror:1
    x = dpp_rot_add<0x122>(x);   // row_ror:2
    x = dpp_rot_add<0x124>(x);   // row_ror:4
    x = dpp_rot_add<0x128>(x);   // row_ror:8
    return x;                    // all 16 lanes hold the row sum
}

// ---------------------------------------------------------------------------
// prep: blocks 0..511   -> bias partials (block b*8+q covers d in [q*32, q*32+32))
//       blocks 512..543 -> W_frag: context_w (f32 [256][256]) -> bf16 MFMA B-frag order
// ---------------------------------------------------------------------------
__global__ __launch_bounds__(256) void prep_kernel(
    const float* __restrict__ aspect, const float* __restrict__ sentence,
    const float* __restrict__ context_w, const float* __restrict__ aspect_w,
    const float* __restrict__ sent_w,
    float* __restrict__ bias_part, ushort* __restrict__ wfrag_ws)
{
    const int blk = blockIdx.x, tid = threadIdx.x;
    if (blk < 512) {
        const int b = blk >> 3, q = blk & 7, e = tid;
        float s = 0.f;
        #pragma unroll 4
        for (int dd = 0; dd < 32; ++dd) {
            const int d = q * 32 + dd;
            s = fmaf(aspect[b * DD + d],   aspect_w[d * DD + e], s);
            s = fmaf(sentence[b * DD + d], sent_w[d * DD + e],   s);
        }
        bias_part[blk * DD + e] = s;
    } else {
        const int flat = (blk - 512) * 256 + tid;    // 0..8191
        const int lane = flat & 63;
        const int kn   = flat >> 6;
        const int kk   = kn >> 4;
        const int n    = kn & 15;
        const int krow = kk * 32 + ((lane >> 4) << 3);
        const int col  = n * 16 + (lane & 15);
        bf16x8 v;
        #pragma unroll
        for (int j = 0; j < 8; ++j)
            v[j] = (short)f2bf(context_w[(size_t)(krow + j) * DD + col]);
        *reinterpret_cast<bf16x8*>(wfrag_ws + (size_t)flat * 8) = v;
    }
}

// ---------------------------------------------------------------------------
// attn_main: 512 blocks x 512 thr (8 waves), 8 tiles of 32 rows.
// Wave = col group (32 cols); covers all 32 rows of the tile. Reg-staged
// global loads (issued one tile ahead), bf16 double-buffered LDS, DPP
// epilogue reduction (no LDS shuffles). 2 barriers/tile.
// ---------------------------------------------------------------------------
__global__ __launch_bounds__(512, 2) void attn_main(
    const float* __restrict__ ctx, const int* __restrict__ mask,
    const float* __restrict__ attend_w,
    const float* __restrict__ bias_part, const ushort* __restrict__ wfrag_ws,
    float* __restrict__ partial_ws, float* __restrict__ esum_ws)
{
    __shared__ __align__(16) char bfb[2][TILE_R * 512];  // 2 x 16KB, 512B pitch, XOR swizzle
    __shared__ float bias_lds[256];
    __shared__ float aw_lds[256];
    __shared__ float mask_lds[256];
    __shared__ float gpart[TILE_R][8];
    __shared__ float esw[8];
    __shared__ float part_d[8][256];

    const int tid  = threadIdx.x;
    const int wave = tid >> 6;
    const int lane = tid & 63;
    const int blk  = blockIdx.x;
    const int b    = blk >> 3;               // 8 blocks per batch element
    const int cg   = wave;                   // col group (32 cols)

    if (tid < 256) {
        float bs = 0.f;
        #pragma unroll
        for (int q = 0; q < 8; ++q) bs += bias_part[(b * 8 + q) * DD + tid];
        bias_lds[tid] = bs;
    } else {
        const int m = tid - 256;
        aw_lds[m]   = attend_w[m];
        mask_lds[m] = (float)mask[blk * 256 + m];
    }

    // ---- preload this wave's 16 B-fragments (cols cg*32 .. +31): 64 VGPR ----
    bf16x8 Bf[8][2];
    {
        const bf16x8* wf = reinterpret_cast<const bf16x8*>(wfrag_ws);
        #pragma unroll
        for (int kk = 0; kk < 8; ++kk) {
            Bf[kk][0] = wf[(kk * 16 + cg * 2 + 0) * 64 + lane];
            Bf[kk][1] = wf[(kk * 16 + cg * 2 + 1) * 64 + lane];
        }
    }

    const float4* src = reinterpret_cast<const float4*>(ctx);

    // ---- prologue: load + convert + write tile 0 ----
    {
        const size_t base4 = (size_t)(blk * NTILE) * 2048;   // 2048 float4 per 32-row tile
        char* dst = bfb[0];
        #pragma unroll
        for (int i = 0; i < 4; ++i) {
            const int idx = i * 512 + tid;
            const float4 v = src[base4 + idx];
            const int row = idx >> 6, c4 = idx & 63;
            uint2 u; u.x = pkbf(v.x, v.y); u.y = pkbf(v.z, v.w);
            *reinterpret_cast<uint2*>(dst + row * 512 + ((c4 * 8) ^ ((row & 7) << 4))) = u;
        }
    }
    __syncthreads();

    float accd[4] = {0.f, 0.f, 0.f, 0.f};
    float es_tot = 0.f;

    for (int it = 0; it < NTILE; ++it) {
        const int cur = it & 1;
        const char* lb = bfb[cur];

        // ---- issue next tile's global loads (consumed in convert phase) ----
        float4 sreg[4];
        if (it + 1 < NTILE) {
            const size_t base4 = (size_t)(blk * NTILE + it + 1) * 2048;
            #pragma unroll
            for (int i = 0; i < 4; ++i) sreg[i] = src[base4 + i * 512 + tid];
        }

        // ---- GEMM: 32 rows x this wave's 32 cols, K=256 ----
        f32x4 acc[2][2];
        #pragma unroll
        for (int rt = 0; rt < 2; ++rt) {
            acc[rt][0] = (f32x4){0.f, 0.f, 0.f, 0.f};
            acc[rt][1] = (f32x4){0.f, 0.f, 0.f, 0.f};
        }
        #pragma unroll
        for (int rt = 0; rt < 2; ++rt) {
            const int row = rt * 16 + (lane & 15);
            const char* ab = lb + row * 512;
            const int asw = (row & 7) << 4;
            #pragma unroll
            for (int kk = 0; kk < 8; ++kk) {
                const bf16x8 a = *reinterpret_cast<const bf16x8*>(
                    ab + ((kk * 64 + ((lane >> 4) << 4)) ^ asw));
                acc[rt][0] = __builtin_amdgcn_mfma_f32_16x16x32_bf16(a, Bf[kk][0], acc[rt][0], 0, 0, 0);
                acc[rt][1] = __builtin_amdgcn_mfma_f32_16x16x32_bf16(a, Bf[kk][1], acc[rt][1], 0, 0, 0);
            }
        }

        // ---- epilogue: partial g over this wave's 32 cols (DPP reduce) ----
        {
            const int c0 = cg * 32 + (lane & 15), c1 = c0 + 16;
            const float bs0 = bias_lds[c0], aw0 = aw_lds[c0];
            const float bs1 = bias_lds[c1], aw1 = aw_lds[c1];
            #pragma unroll
            for (int rt = 0; rt < 2; ++rt) {
                #pragma unroll
                for (int j = 0; j < 4; ++j) {
                    float gv = tanh_fast(acc[rt][0][j] + bs0) * aw0
                             + tanh_fast(acc[rt][1][j] + bs1) * aw1;
                    gv = row16_sum(gv);
                    if ((lane & 15) == 0)
                        gpart[rt * 16 + ((lane >> 4) << 2) + j][cg] = gv;
                }
            }
        }
        __syncthreads();   // barrier A: gpart complete

        // ---- evals + fused weighted sum: wave handles tile rows wave*4..+3 ----
        #pragma unroll
        for (int rr = 0; rr < 4; ++rr) {
            const int r = wave * 4 + rr;
            const float4 g0 = *reinterpret_cast<const float4*>(&gpart[r][0]);
            const float4 g1 = *reinterpret_cast<const float4*>(&gpart[r][4]);
            const float g = ((g0.x + g0.y) + (g0.z + g0.w))
                          + ((g1.x + g1.y) + (g1.z + g1.w));
            const float ev = __expf(g) * mask_lds[it * TILE_R + r];
            es_tot += ev;
            const uint2 hv = *reinterpret_cast<const uint2*>(
                lb + r * 512 + ((lane * 8) ^ ((r & 7) << 4)));
            accd[0] = fmaf(bf2f(hv.x & 0xffffu), ev, accd[0]);
            accd[1] = fmaf(bf2f(hv.x >> 16),     ev, accd[1]);
            accd[2] = fmaf(bf2f(hv.y & 0xffffu), ev, accd[2]);
            accd[3] = fmaf(bf2f(hv.y >> 16),     ev, accd[3]);
        }

        // ---- convert + write next tile into the other buffer ----
        if (it + 1 < NTILE) {
            char* dst = bfb[cur ^ 1];
            #pragma unroll
            for (int i = 0; i < 4; ++i) {
                const int idx = i * 512 + tid;
                const int row = idx >> 6, c4 = idx & 63;
                uint2 u; u.x = pkbf(sreg[i].x, sreg[i].y); u.y = pkbf(sreg[i].z, sreg[i].w);
                *reinterpret_cast<uint2*>(dst + row * 512 + ((c4 * 8) ^ ((row & 7) << 4))) = u;
            }
        }
        __syncthreads();   // barrier B: next buffer staged, gpart reusable
    }

    // ---- block epilogue ----
    *reinterpret_cast<float4*>(&part_d[wave][lane * 4]) =
        (float4){accd[0], accd[1], accd[2], accd[3]};
    if (lane == 0) esw[wave] = es_tot;
    __syncthreads();
    if (tid < 256) {
        float s = 0.f;
        #pragma unroll
        for (int w = 0; w < 8; ++w) s += part_d[w][tid];
        partial_ws[blk * DD + tid] = s;
    }
    if (tid == 0) {
        float e = 0.f;
        #pragma unroll
        for (int w = 0; w < 8; ++w) e += esw[w];
        esum_ws[blk] = e;
    }
}

// ---------------------------------------------------------------------------
// finalize: out[b,d] = (sum_i partial) / (sum_i esum + EPS) + sentence[b,d]
// ---------------------------------------------------------------------------
__global__ __launch_bounds__(256) void finalize_kernel(
    const float* __restrict__ sentence, const float* __restrict__ partial_ws,
    const float* __restrict__ esum_ws, float* __restrict__ out)
{
    const int b = blockIdx.x, d = threadIdx.x;
    float es = 0.f, s = 0.f;
    #pragma unroll
    for (int i = 0; i < 8; ++i) {
        es += esum_ws[b * 8 + i];
        s  += partial_ws[(size_t)(b * 8 + i) * DD + d];
    }
    out[b * DD + d] = s / (es + EPSV) + sentence[b * DD + d];
}

extern "C" void kernel_launch(void* const* d_in, const int* in_sizes, int n_in,
                              void* d_out, int out_size, void* d_ws, size_t ws_size,
                              hipStream_t stream)
{
    const float* ctx       = (const float*)d_in[0];
    const float* aspect    = (const float*)d_in[1];
    const float* sentence  = (const float*)d_in[2];
    const int*   mask      = (const int*)  d_in[3];
    const float* context_w = (const float*)d_in[4];
    const float* aspect_w  = (const float*)d_in[5];
    const float* sent_w    = (const float*)d_in[6];
    const float* attend_w  = (const float*)d_in[7];
    float* out = (float*)d_out;

    char* ws = (char*)d_ws;
    ushort* wfrag_ws   = (ushort*)(ws);                           // 131072 B
    float*  bias_part  = (float*) (ws + 131072);                  // 524288 B
    float*  esum_ws    = (float*) (ws + 131072 + 524288);         //   2048 B
    float*  partial_ws = (float*) (ws + 131072 + 524288 + 2048);  // 524288 B

    prep_kernel<<<544, 256, 0, stream>>>(aspect, sentence, context_w, aspect_w, sent_w,
                                         bias_part, wfrag_ws);
    attn_main<<<NBLK, 512, 0, stream>>>(ctx, mask, attend_w, bias_part, wfrag_ws,
                                        partial_ws, esum_ws);
    finalize_kernel<<<BB, 256, 0, stream>>>(sentence, partial_ws, esum_ws, out);
}

// Round 6
// 46.888 us; speedup vs baseline: 1.4773x; 1.0842x over previous
//
#include <hip/hip_runtime.h>
#include <hip/hip_bf16.h>

// Problem dims (fixed by the reference): B=64, T=2048, D=256
#define BB  64
#define TT  2048
#define DD  256
#define EPSV 1e-7f
#define TILE_R 32   // rows per tile
#define NTILE  8    // tiles per block
#define NBLK   512  // blocks: NBLK*NTILE*TILE_R == BB*TT ; 2 blocks/CU

typedef __attribute__((ext_vector_type(8))) short bf16x8;   // MFMA A/B fragment (4 VGPR)
typedef __attribute__((ext_vector_type(4))) float f32x4;    // MFMA C/D fragment

__device__ __forceinline__ ushort f2bf(float f) {           // RNE (prep only)
    union { float f; unsigned u; } v; v.f = f;
    unsigned u = v.u;
    unsigned r = (u + 0x7FFFu + ((u >> 16) & 1u)) >> 16;
    return (ushort)r;
}

__device__ __forceinline__ float bf2f(unsigned h16) {       // low 16 bits = bf16
    union { unsigned u; float f; } v; v.u = h16 << 16;
    return v.f;
}

// pack two f32 -> two bf16 (round-half-up): [bf(lo), bf(hi)]
__device__ __forceinline__ unsigned pkbf(float lo, float hi) {
    union { float f; unsigned u; } a, b;
    a.f = lo; b.f = hi;
    return __builtin_amdgcn_perm(b.u + 0x8000u, a.u + 0x8000u, 0x07060302u);
}

__device__ __forceinline__ float tanh_fast(float x) {
    float e = __expf(2.0f * x);
    return 1.0f - 2.0f * __builtin_amdgcn_rcpf(e + 1.0f);
}

// sum over the 16-lane DPP row via rotations (pure VALU, no LDS traffic)
template<int CTRL>
__device__ __forceinline__ float dpp_rot_add(float x) {
    union { float f; int i; } a; a.f = x;
    int r = __builtin_amdgcn_update_dpp(0, a.i, CTRL, 0xF, 0xF, true);
    union { int i; float f; } b; b.i = r;
    return x + b.f;
}
__device__ __forceinline__ float row16_sum(float x) {
    x = dpp_rot_add<0x121>(x);   // row_ror:1
    x = dpp_rot_add<0x122>(x);   // row_ror:2
    x = dpp_rot_add<0x124>(x);   // row_ror:4
    x = dpp_rot_add<0x128>(x);   // row_ror:8
    return x;                    // all 16 lanes hold the row sum
}

// ---------------------------------------------------------------------------
// prep: blocks 0..511   -> bias partials (block b*8+q covers d in [q*32, q*32+32))
//       blocks 512..543 -> W_frag: context_w (f32 [256][256]) -> bf16 MFMA B-frag order
// ---------------------------------------------------------------------------
__global__ __launch_bounds__(256) void prep_kernel(
    const float* __restrict__ aspect, const float* __restrict__ sentence,
    const float* __restrict__ context_w, const float* __restrict__ aspect_w,
    const float* __restrict__ sent_w,
    float* __restrict__ bias_part, ushort* __restrict__ wfrag_ws)
{
    const int blk = blockIdx.x, tid = threadIdx.x;
    if (blk < 512) {
        const int b = blk >> 3, q = blk & 7, e = tid;
        float s = 0.f;
        #pragma unroll 4
        for (int dd = 0; dd < 32; ++dd) {
            const int d = q * 32 + dd;
            s = fmaf(aspect[b * DD + d],   aspect_w[d * DD + e], s);
            s = fmaf(sentence[b * DD + d], sent_w[d * DD + e],   s);
        }
        bias_part[blk * DD + e] = s;
    } else {
        const int flat = (blk - 512) * 256 + tid;    // 0..8191
        const int lane = flat & 63;
        const int kn   = flat >> 6;
        const int kk   = kn >> 4;
        const int n    = kn & 15;
        const int krow = kk * 32 + ((lane >> 4) << 3);
        const int col  = n * 16 + (lane & 15);
        bf16x8 v;
        #pragma unroll
        for (int j = 0; j < 8; ++j)
            v[j] = (short)f2bf(context_w[(size_t)(krow + j) * DD + col]);
        *reinterpret_cast<bf16x8*>(wfrag_ws + (size_t)flat * 8) = v;
    }
}

// ---------------------------------------------------------------------------
// attn_main: 512 blocks x 512 thr (8 waves), 8 tiles of 32 rows.
// Triple-buffered bf16 tiles -> ONE barrier per tile. Per iter:
//   [convert(it+1) | issue loads(it+2) | GEMM(it) | tanh+gpartT] BAR [evals | wsum]
// Wave = col group (32 cols) for GEMM; evals per-lane (row = lane&31);
// wsum rows wave*4..+3 with ev via readlane broadcast.
// ---------------------------------------------------------------------------
__global__ __launch_bounds__(512, 2) void attn_main(
    const float* __restrict__ ctx, const int* __restrict__ mask,
    const float* __restrict__ attend_w,
    const float* __restrict__ bias_part, const ushort* __restrict__ wfrag_ws,
    float* __restrict__ partial_ws, float* __restrict__ esum_ws)
{
    __shared__ __align__(16) char bfb[3][TILE_R * 512];  // 3 x 16KB, 512B pitch, XOR swizzle
    __shared__ float gpartT[2][8][TILE_R];               // [phase][cg][row]
    __shared__ float bias_lds[256];
    __shared__ float aw_lds[256];
    __shared__ float mask_lds[256];
    __shared__ float part_d[8][256];

    const int tid  = threadIdx.x;
    const int wave = tid >> 6;
    const int lane = tid & 63;
    const int blk  = blockIdx.x;
    const int b    = blk >> 3;               // 8 blocks per batch element
    const int cg   = wave;                   // col group (32 cols)

    if (tid < 256) {
        float bs = 0.f;
        #pragma unroll
        for (int q = 0; q < 8; ++q) bs += bias_part[(b * 8 + q) * DD + tid];
        bias_lds[tid] = bs;
    } else {
        const int m = tid - 256;
        aw_lds[m]   = attend_w[m];
        mask_lds[m] = (float)mask[blk * 256 + m];
    }

    // ---- preload this wave's 16 B-fragments (cols cg*32 .. +31): 64 VGPR ----
    bf16x8 Bf[8][2];
    {
        const bf16x8* wf = reinterpret_cast<const bf16x8*>(wfrag_ws);
        #pragma unroll
        for (int kk = 0; kk < 8; ++kk) {
            Bf[kk][0] = wf[(kk * 16 + cg * 2 + 0) * 64 + lane];
            Bf[kk][1] = wf[(kk * 16 + cg * 2 + 1) * 64 + lane];
        }
    }

    const float4* src = reinterpret_cast<const float4*>(ctx);
    const int cc  = tid;            // 8-float chunk index base (1024 chunks/tile)
    const int crow0 = cc >> 5,        c80 = cc & 31;          // i = 0 chunk
    const int crow1 = (512 + cc) >> 5, c81 = (512 + cc) & 31; // i = 1 chunk

    // ---- prologue: load tile 0, convert -> buf0, issue tile 1 ----
    float4 sreg[4];
    {
        const size_t base4 = (size_t)(blk * NTILE) * 2048;
        #pragma unroll
        for (int i = 0; i < 2; ++i) {
            const int c = i * 512 + tid;
            sreg[2 * i + 0] = src[base4 + 2 * c + 0];
            sreg[2 * i + 1] = src[base4 + 2 * c + 1];
        }
        char* dst = bfb[0];
        #pragma unroll
        for (int i = 0; i < 2; ++i) {
            const int row = i ? crow1 : crow0, c8 = i ? c81 : c80;
            uint4 u;
            u.x = pkbf(sreg[2 * i].x,     sreg[2 * i].y);
            u.y = pkbf(sreg[2 * i].z,     sreg[2 * i].w);
            u.z = pkbf(sreg[2 * i + 1].x, sreg[2 * i + 1].y);
            u.w = pkbf(sreg[2 * i + 1].z, sreg[2 * i + 1].w);
            *reinterpret_cast<uint4*>(dst + row * 512 + ((c8 * 16) ^ ((row & 7) << 4))) = u;
        }
        const size_t b1 = base4 + 2048;
        #pragma unroll
        for (int i = 0; i < 2; ++i) {
            const int c = i * 512 + tid;
            sreg[2 * i + 0] = src[b1 + 2 * c + 0];
            sreg[2 * i + 1] = src[b1 + 2 * c + 1];
        }
    }
    __syncthreads();

    // loop-invariant epilogue constants
    const int c0 = cg * 32 + (lane & 15), c1 = c0 + 16;
    const float bs0 = bias_lds[c0], awc0 = aw_lds[c0];
    const float bs1 = bias_lds[c1], awc1 = aw_lds[c1];

    float accd[4] = {0.f, 0.f, 0.f, 0.f};
    float es_acc = 0.f;
    int cb = 0;

    for (int it = 0; it < NTILE; ++it) {
        const int nb = (cb == 2) ? 0 : cb + 1;
        const int gp = it & 1;
        const char* lb = bfb[cb];

        // ---- (1) convert sreg (tile it+1 data) -> buf nb ----
        if (it + 1 < NTILE) {
            char* dst = bfb[nb];
            #pragma unroll
            for (int i = 0; i < 2; ++i) {
                const int row = i ? crow1 : crow0, c8 = i ? c81 : c80;
                uint4 u;
                u.x = pkbf(sreg[2 * i].x,     sreg[2 * i].y);
                u.y = pkbf(sreg[2 * i].z,     sreg[2 * i].w);
                u.z = pkbf(sreg[2 * i + 1].x, sreg[2 * i + 1].y);
                u.w = pkbf(sreg[2 * i + 1].z, sreg[2 * i + 1].w);
                *reinterpret_cast<uint4*>(dst + row * 512 + ((c8 * 16) ^ ((row & 7) << 4))) = u;
            }
        }
        // ---- (2) issue tile it+2 global loads ----
        if (it + 2 < NTILE) {
            const size_t base4 = (size_t)(blk * NTILE + it + 2) * 2048;
            #pragma unroll
            for (int i = 0; i < 2; ++i) {
                const int c = i * 512 + tid;
                sreg[2 * i + 0] = src[base4 + 2 * c + 0];
                sreg[2 * i + 1] = src[base4 + 2 * c + 1];
            }
        }

        // ---- (3) GEMM: 32 rows x this wave's 32 cols, K=256 ----
        f32x4 acc[2][2];
        #pragma unroll
        for (int rt = 0; rt < 2; ++rt) {
            acc[rt][0] = (f32x4){0.f, 0.f, 0.f, 0.f};
            acc[rt][1] = (f32x4){0.f, 0.f, 0.f, 0.f};
        }
        #pragma unroll
        for (int rt = 0; rt < 2; ++rt) {
            const int row = rt * 16 + (lane & 15);
            const char* ab = lb + row * 512;
            const int asw = (row & 7) << 4;
            #pragma unroll
            for (int kk = 0; kk < 8; ++kk) {
                const bf16x8 a = *reinterpret_cast<const bf16x8*>(
                    ab + ((kk * 64 + ((lane >> 4) << 4)) ^ asw));
                acc[rt][0] = __builtin_amdgcn_mfma_f32_16x16x32_bf16(a, Bf[kk][0], acc[rt][0], 0, 0, 0);
                acc[rt][1] = __builtin_amdgcn_mfma_f32_16x16x32_bf16(a, Bf[kk][1], acc[rt][1], 0, 0, 0);
            }
        }

        // ---- (4) tanh epilogue + DPP reduce -> gpartT[gp][cg][*] (2 x b128) ----
        #pragma unroll
        for (int rt = 0; rt < 2; ++rt) {
            float g0 = row16_sum(tanh_fast(acc[rt][0][0] + bs0) * awc0
                               + tanh_fast(acc[rt][1][0] + bs1) * awc1);
            float g1 = row16_sum(tanh_fast(acc[rt][0][1] + bs0) * awc0
                               + tanh_fast(acc[rt][1][1] + bs1) * awc1);
            float g2 = row16_sum(tanh_fast(acc[rt][0][2] + bs0) * awc0
                               + tanh_fast(acc[rt][1][2] + bs1) * awc1);
            float g3 = row16_sum(tanh_fast(acc[rt][0][3] + bs0) * awc0
                               + tanh_fast(acc[rt][1][3] + bs1) * awc1);
            if ((lane & 15) == 0) {
                const int r = rt * 16 + ((lane >> 4) << 2);
                *reinterpret_cast<float4*>(&gpartT[gp][cg][r]) = (float4){g0, g1, g2, g3};
            }
        }
        __syncthreads();   // the ONLY barrier per tile

        // ---- (5) evals: every lane computes ev for row lane&31 ----
        const int erow = lane & 31;
        float gsum = 0.f;
        #pragma unroll
        for (int c = 0; c < 8; ++c) gsum += gpartT[gp][c][erow];
        const float ev = __expf(gsum) * mask_lds[it * TILE_R + erow];
        es_acc += (lane < 32) ? ev : 0.f;

        // ---- (6) fused weighted sum: wave handles tile rows wave*4..+3 ----
        #pragma unroll
        for (int rr = 0; rr < 4; ++rr) {
            const int r = wave * 4 + rr;
            const float e = __shfl(ev, r);   // uniform index -> readlane broadcast
            const uint2 hv = *reinterpret_cast<const uint2*>(
                lb + r * 512 + ((lane * 8) ^ ((r & 7) << 4)));
            accd[0] = fmaf(bf2f(hv.x & 0xffffu), e, accd[0]);
            accd[1] = fmaf(bf2f(hv.x >> 16),     e, accd[1]);
            accd[2] = fmaf(bf2f(hv.y & 0xffffu), e, accd[2]);
            accd[3] = fmaf(bf2f(hv.y >> 16),     e, accd[3]);
        }

        cb = nb;
    }

    // ---- block epilogue ----
    *reinterpret_cast<float4*>(&part_d[wave][lane * 4]) =
        (float4){accd[0], accd[1], accd[2], accd[3]};
    __syncthreads();
    if (tid < 256) {
        float s = 0.f;
        #pragma unroll
        for (int w = 0; w < 8; ++w) s += part_d[w][tid];
        partial_ws[blk * DD + tid] = s;
    }
    if (wave == 0) {
        float s = row16_sum(es_acc);
        s += __shfl_xor(s, 16);
        if (lane == 0) esum_ws[blk] = s;
    }
}

// ---------------------------------------------------------------------------
// finalize: out[b,d] = (sum_i partial) / (sum_i esum + EPS) + sentence[b,d]
// ---------------------------------------------------------------------------
__global__ __launch_bounds__(256) void finalize_kernel(
    const float* __restrict__ sentence, const float* __restrict__ partial_ws,
    const float* __restrict__ esum_ws, float* __restrict__ out)
{
    const int b = blockIdx.x, d = threadIdx.x;
    float es = 0.f, s = 0.f;
    #pragma unroll
    for (int i = 0; i < 8; ++i) {
        es += esum_ws[b * 8 + i];
        s  += partial_ws[(size_t)(b * 8 + i) * DD + d];
    }
    out[b * DD + d] = s / (es + EPSV) + sentence[b * DD + d];
}

extern "C" void kernel_launch(void* const* d_in, const int* in_sizes, int n_in,
                              void* d_out, int out_size, void* d_ws, size_t ws_size,
                              hipStream_t stream)
{
    const float* ctx       = (const float*)d_in[0];
    const float* aspect    = (const float*)d_in[1];
    const float* sentence  = (const float*)d_in[2];
    const int*   mask      = (const int*)  d_in[3];
    const float* context_w = (const float*)d_in[4];
    const float* aspect_w  = (const float*)d_in[5];
    const float* sent_w    = (const float*)d_in[6];
    const float* attend_w  = (const float*)d_in[7];
    float* out = (float*)d_out;

    char* ws = (char*)d_ws;
    ushort* wfrag_ws   = (ushort*)(ws);                           // 131072 B
    float*  bias_part  = (float*) (ws + 131072);                  // 524288 B
    float*  esum_ws    = (float*) (ws + 131072 + 524288);         //   2048 B
    float*  partial_ws = (float*) (ws + 131072 + 524288 + 2048);  // 524288 B

    prep_kernel<<<544, 256, 0, stream>>>(aspect, sentence, context_w, aspect_w, sent_w,
                                         bias_part, wfrag_ws);
    attn_main<<<NBLK, 512, 0, stream>>>(ctx, mask, attend_w, bias_part, wfrag_ws,
                                        partial_ws, esum_ws);
    finalize_kernel<<<BB, 256, 0, stream>>>(sentence, partial_ws, esum_ws, out);
}